// Round 15
// baseline (127.176 us; speedup 1.0000x reference)
//
#include <hip/hip_runtime.h>

// CapsuleNetwork routing, fused, one block per batch. B=2048, S=200, D=64, K=4.
//
// hat[b,k,s,:] = emb[b,s,:] @ W_k + b_k is never materialized:
//   logits[k,s] = emb[s]·u[k] + off[k],  u[k] = W_k @ G[k], off[k] = b_k·G[k]
//   v[k]        = e[k] @ W_k + ts[k]·b_k, e[k] = sum_s sw[k,s] emb[s]
// G = running sum of interests (cw telescopes).
//
// Round-15 = round-14 BD sweep + SINGLE-PHASE E on waves 0-3 with wreg[64]
// (full W column per k). r8's version of this spilled because (512,4) caps
// VGPR at 64; at (512,2) the cap is 128 and the live set (~112) fits.
//  - barriers per iter 3 -> 2 (b2 deleted: pe-reduce, dot, squash, A-fold
//    all same-wave, same phase).
//  - pe-reduce DS reads halve (4 waves x 8 vs 8 waves x 8).
//  - it==0 specialized: only pe[w][0] written/read (sw uniform over k).

#define NB 2048
#define NS 200
#define ND 64
#define NK 4
#define NT 512
#define LOG2E 1.44269504f

__device__ __forceinline__ int rot(int s) { return (s + (s >> 3)) & 15; }

__device__ __forceinline__ void gload16(const float* g_, float* l_) {
  __builtin_amdgcn_global_load_lds(
      (const __attribute__((address_space(1))) unsigned int*)g_,
      (__attribute__((address_space(3))) unsigned int*)l_, 16, 0, 0);
}

template <int CTRL>
__device__ __forceinline__ float dppadd(float v) {
  int p = __builtin_amdgcn_update_dpp(0, __float_as_int(v), CTRL, 0xF, 0xF, true);
  return v + __int_as_float(p);
}

#if __has_builtin(__builtin_amdgcn_permlane16_swap)
__device__ __forceinline__ float pl16add(float v) {
  auto r = __builtin_amdgcn_permlane16_swap(__float_as_int(v), __float_as_int(v),
                                            false, false);
  return __int_as_float(r[0]) + __int_as_float(r[1]);
}
#else
__device__ __forceinline__ float pl16add(float v) { return v + __shfl_xor(v, 16, 64); }
#endif

#if __has_builtin(__builtin_amdgcn_permlane32_swap)
__device__ __forceinline__ float pl32add(float v) {
  auto r = __builtin_amdgcn_permlane32_swap(__float_as_int(v), __float_as_int(v),
                                            false, false);
  return __int_as_float(r[0]) + __int_as_float(r[1]);
}
#else
__device__ __forceinline__ float pl32add(float v) { return v + __shfl_xor(v, 32, 64); }
#endif

// sum over lane bits 2..5 (the 16 chunk positions)
__device__ __forceinline__ float red_j(float v) {
  v = dppadd<0x124>(v);  // row_ror:4  (bit 2)
  v = dppadd<0x128>(v);  // row_ror:8  (bit 3)
  v = pl16add(v);        // bit 4
  v = pl32add(v);        // bit 5
  return v;
}
// sum over lane bits 0,1 (row-quad)
__device__ __forceinline__ float red_q(float v) {
  v = dppadd<0xB1>(v);  // quad_perm xor1
  v = dppadd<0x4E>(v);  // quad_perm xor2
  return v;
}
__device__ __forceinline__ float red64(float v) { return red_j(red_q(v)); }

__global__ __launch_bounds__(NT, 2) void caps_kernel(
    const float* __restrict__ his, const float* __restrict__ itemeb,
    const int* __restrict__ mask, const float* __restrict__ W,
    const float* __restrict__ bias, float* __restrict__ out) {
  __shared__ float semb[NS * ND];  // 51200B: row s, chunk c at slot (c+rot(s))&15
  __shared__ float pe[8][NK][ND];  // 8192B: per-wave fused-BD partials
  __shared__ float sG[NK][ND];     // 1024B: A-fold broadcast source
  __shared__ float su[NK][ND];     // 1024B: u[k] (log2e-scaled); E bounce
  __shared__ float spv[NK][ND];    // 1024B: final interest stash
  __shared__ float smsk[NS];       // 800B
  __shared__ float4 pts4[8];       // 128B
  __shared__ __align__(16) float soff[NK];
  __shared__ float satt[NK];
  __shared__ int sidx;
  // ~63.4 KB -> 2 blocks/CU

  const int t = threadIdx.x;
  const int w = t >> 6, l = t & 63;
  const int g = l & 3, j = l >> 2;   // row-quad / chunk (DPP-aligned)
  const int gid = (w << 2) | g;      // 0..31
  const int ke = w & 3;              // E role (waves 0-3 only)
  const int b = blockIdx.x;
  const float* eb = his + (size_t)b * NS * ND;

  // ---- full W column in regs (waves 0-3): wreg[c] = W[c][64*ke+l] ----
  float wreg[64];
  if (w < 4) {
#pragma unroll
    for (int c = 0; c < 64; ++c)
      wreg[c] = W[(size_t)c * (NK * ND) + ke * ND + l];
  }
  float breg = bias[ke * ND + l];
  float iq = itemeb[(size_t)b * ND + l];

  // ---- stage all 200 rows (linear LDS dest, rotated global source) ----
  {
    const int sg = l >> 4, sj = l & 15;
    for (int i = w; i < 50; i += 8) {
      int s = 4 * i + sg;
      int q = (sj - rot(s)) & 15;
      gload16(eb + (s << 6) + (q << 2), &semb[i * 256]);
    }
  }
  if (t < NS) smsk[t] = (mask[(size_t)b * NS + t] != 0) ? 1.0f : 0.0f;
  __syncthreads();

  const int ntr = (w < 2) ? 7 : 6;  // wave-uniform trips (gid<8 covers s=199)
  float greg = 0.f;                 // register copy of G[ke][l] (waves 0-3)

  for (int it = 0; it < 3; ++it) {
    // ---- fused BD sweep: logits + softmax + e-accumulate, one emb read ----
    float4 a0 = {0, 0, 0, 0}, a1 = {0, 0, 0, 0}, a2 = {0, 0, 0, 0},
           a3 = {0, 0, 0, 0};
    float t0 = 0, t1 = 0, t2 = 0, t3 = 0;

    if (it == 0) {
      for (int tt = 0; tt < ntr; ++tt) {
        int s = gid + 32 * tt;
        float4 eq = *(const float4*)&semb[(s << 6) + 4 * ((j + rot(s)) & 15)];
        float sw = 0.25f * smsk[s];
        a0.x += sw * eq.x; a0.y += sw * eq.y;
        a0.z += sw * eq.z; a0.w += sw * eq.w;
        t0 += sw;
      }
      a0.x = red_q(a0.x); a0.y = red_q(a0.y);
      a0.z = red_q(a0.z); a0.w = red_q(a0.w);
      t0 = red_q(t0);
    } else {
      float4 u0 = *(const float4*)&su[0][4 * j];  // log2e-scaled u chunks
      float4 u1 = *(const float4*)&su[1][4 * j];
      float4 u2 = *(const float4*)&su[2][4 * j];
      float4 u3 = *(const float4*)&su[3][4 * j];
      float4 sof = *(const float4*)&soff[0];      // log2e-scaled
      for (int tt = 0; tt < ntr; ++tt) {
        int s = gid + 32 * tt;
        float4 eq = *(const float4*)&semb[(s << 6) + 4 * ((j + rot(s)) & 15)];
        float mk = smsk[s];
        float lg0 = eq.x * u0.x + eq.y * u0.y + eq.z * u0.z + eq.w * u0.w;
        float lg1 = eq.x * u1.x + eq.y * u1.y + eq.z * u1.z + eq.w * u1.w;
        float lg2 = eq.x * u2.x + eq.y * u2.y + eq.z * u2.z + eq.w * u2.w;
        float lg3 = eq.x * u3.x + eq.y * u3.y + eq.z * u3.z + eq.w * u3.w;
        lg0 = red_j(lg0) + sof.x;
        lg1 = red_j(lg1) + sof.y;
        lg2 = red_j(lg2) + sof.z;
        lg3 = red_j(lg3) + sof.w;
        // softmax, log2 domain, no max-sub (|lg| bounded << 126)
        float e0 = exp2f(lg0), e1 = exp2f(lg1);
        float e2 = exp2f(lg2), e3 = exp2f(lg3);
        float r = mk / (e0 + e1 + e2 + e3);
        float sw0 = e0 * r, sw1 = e1 * r, sw2 = e2 * r, sw3 = e3 * r;
        a0.x += sw0 * eq.x; a0.y += sw0 * eq.y; a0.z += sw0 * eq.z; a0.w += sw0 * eq.w;
        a1.x += sw1 * eq.x; a1.y += sw1 * eq.y; a1.z += sw1 * eq.z; a1.w += sw1 * eq.w;
        a2.x += sw2 * eq.x; a2.y += sw2 * eq.y; a2.z += sw2 * eq.z; a2.w += sw2 * eq.w;
        a3.x += sw3 * eq.x; a3.y += sw3 * eq.y; a3.z += sw3 * eq.z; a3.w += sw3 * eq.w;
        t0 += sw0; t1 += sw1; t2 += sw2; t3 += sw3;
      }
      a0.x = red_q(a0.x); a0.y = red_q(a0.y); a0.z = red_q(a0.z); a0.w = red_q(a0.w);
      a1.x = red_q(a1.x); a1.y = red_q(a1.y); a1.z = red_q(a1.z); a1.w = red_q(a1.w);
      a2.x = red_q(a2.x); a2.y = red_q(a2.y); a2.z = red_q(a2.z); a2.w = red_q(a2.w);
      a3.x = red_q(a3.x); a3.y = red_q(a3.y); a3.z = red_q(a3.z); a3.w = red_q(a3.w);
      t0 = red_q(t0); t1 = red_q(t1); t2 = red_q(t2); t3 = red_q(t3);
    }
    if (g == 0) {  // 16 lanes, one float4 per chunk j
      *(float4*)&pe[w][0][4 * j] = a0;
      if (it > 0) {
        *(float4*)&pe[w][1][4 * j] = a1;
        *(float4*)&pe[w][2][4 * j] = a2;
        *(float4*)&pe[w][3][4 * j] = a3;
      }
    }
    if (l == 0) pts4[w] = make_float4(t0, t1, t2, t3);
    __syncthreads();  // b1

    // ---- E (waves 0-3, single phase): pe-reduce, full-column dot with
    //      wreg[64], squash, G in reg, fold A + soff ----
    if (w < 4) {
      const int kk = (it == 0) ? 0 : ke;
      float sse = 0.f;
#pragma unroll
      for (int w2 = 0; w2 < 8; ++w2) sse += pe[w2][kk][l];
      su[ke][l] = sse;  // same-wave write -> broadcast read below
      float ts_ = 0.f;
#pragma unroll
      for (int w2 = 0; w2 < 8; ++w2) ts_ += ((const float*)&pts4[w2])[kk];
      float accv = ts_ * breg;
#pragma unroll
      for (int q2 = 0; q2 < 16; ++q2) {
        float4 e4 = *(const float4*)&su[ke][4 * q2];  // broadcast
        accv += e4.x * wreg[4 * q2 + 0] + e4.y * wreg[4 * q2 + 1] +
                e4.z * wreg[4 * q2 + 2] + e4.w * wreg[4 * q2 + 3];
      }
      float n2 = red64(accv * accv);
      float scale = n2 / (1.f + n2) / sqrtf(n2 + 1e-9f);
      float inter = scale * accv;
      if (it < 2) {
        greg += inter;       // register RMW — no LDS read
        sG[ke][l] = greg;    // broadcast source for A-fold (same wave)
        float ob = red64(breg * greg);
        if (l == 0) soff[ke] = ob * LOG2E;
        // A-fold: su[k][l] = log2e * (W-row-l (cols 64k..) . G[k])
        // (su reads above all precede this write in wave program order)
        const float4* Wr = (const float4*)(W + (size_t)l * (NK * ND) + ke * ND);
        const float4* Gk = (const float4*)&sG[ke][0];  // same-wave broadcast
        float a = 0.f;
#pragma unroll
        for (int d4 = 0; d4 < 16; ++d4) {
          float4 wv = Wr[d4], gv = Gk[d4];
          a += wv.x * gv.x + wv.y * gv.y + wv.z * gv.z + wv.w * gv.w;
        }
        su[ke][l] = LOG2E * a;
      } else {
        out[((size_t)b * NK + ke) * ND + l] = inter;
        float dot_ = red64(inter * iq);
        spv[ke][l] = inter;  // stash for argmax gather
        if (l == 0) satt[ke] = dot_;
      }
    }
    __syncthreads();  // b2 (end of iter: protects su/sG/pe reuse + readout)
  }

  // ---- readout: first-max argmax (== np.argmax) + gather ----
  if (t == 0) {
    int bi = 0;
    float bv = satt[0];
#pragma unroll
    for (int kk = 1; kk < NK; ++kk)
      if (satt[kk] > bv) { bv = satt[kk]; bi = kk; }
    sidx = bi;
  }
  __syncthreads();
  if (t < ND) out[(size_t)NB * NK * ND + (size_t)b * ND + t] = spv[sidx][t];
}

extern "C" void kernel_launch(void* const* d_in, const int* in_sizes, int n_in,
                              void* d_out, int out_size, void* d_ws, size_t ws_size,
                              hipStream_t stream) {
  (void)in_sizes; (void)n_in; (void)out_size; (void)d_ws; (void)ws_size;
  const float* his = (const float*)d_in[0];
  const float* itemeb = (const float*)d_in[1];
  const int* mask = (const int*)d_in[2];
  const float* W = (const float*)d_in[3];
  const float* bias = (const float*)d_in[4];
  float* out = (float*)d_out;
  caps_kernel<<<NB, NT, 0, stream>>>(his, itemeb, mask, W, bias, out);
}

// Round 16
// 88.844 us; speedup vs baseline: 1.4315x; 1.4315x over previous
//
#include <hip/hip_runtime.h>

// CapsuleNetwork routing, fused, one block per batch. B=2048, S=200, D=64, K=4.
//
// hat[b,k,s,:] = emb[b,s,:] @ W_k + b_k is never materialized:
//   logits[k,s] = emb[s]·u[k] + off[k],  u[k] = W_k @ G[k], off[k] = b_k·G[k]
//   v[k]        = e[k] @ W_k + ts[k]·b_k, e[k] = sum_s sw[k,s] emb[s]
// G = running sum of interests (cw telescopes).
//
// FINAL = round-11 config (best measured: 88.9us). Fused BD sweep (one emb
// b128 read per row per iter; u[k] in 16 VGPRs; logits/softmax/e-acc in one
// pass) with ALL cross-lane reductions on the VALU via DPP + permlane
// (shfl_xor would be DS-pipe ds_swizzle — measured regression r10).
// Constraint box (measured): 2 blocks/CU (3 thrashes L2: FETCH 53->358MB);
// VGPR must stay <=64 (>64 -> 1 block/CU, r10/r15); 3 barriers/iter minimum
// at VGPR<=64 (r8/r15); BD inst cuts beyond this are Δ0 (r14).

#define NB 2048
#define NS 200
#define ND 64
#define NK 4
#define NT 512

__device__ __forceinline__ int rot(int s) { return (s + (s >> 3)) & 15; }

__device__ __forceinline__ void gload16(const float* g_, float* l_) {
  __builtin_amdgcn_global_load_lds(
      (const __attribute__((address_space(1))) unsigned int*)g_,
      (__attribute__((address_space(3))) unsigned int*)l_, 16, 0, 0);
}

template <int CTRL>
__device__ __forceinline__ float dppadd(float v) {
  int p = __builtin_amdgcn_update_dpp(0, __float_as_int(v), CTRL, 0xF, 0xF, true);
  return v + __int_as_float(p);
}

#if __has_builtin(__builtin_amdgcn_permlane16_swap)
__device__ __forceinline__ float pl16add(float v) {
  auto r = __builtin_amdgcn_permlane16_swap(__float_as_int(v), __float_as_int(v),
                                            false, false);
  return __int_as_float(r[0]) + __int_as_float(r[1]);
}
#else
__device__ __forceinline__ float pl16add(float v) { return v + __shfl_xor(v, 16, 64); }
#endif

#if __has_builtin(__builtin_amdgcn_permlane32_swap)
__device__ __forceinline__ float pl32add(float v) {
  auto r = __builtin_amdgcn_permlane32_swap(__float_as_int(v), __float_as_int(v),
                                            false, false);
  return __int_as_float(r[0]) + __int_as_float(r[1]);
}
#else
__device__ __forceinline__ float pl32add(float v) { return v + __shfl_xor(v, 32, 64); }
#endif

// sum over lane bits 2..5 (the 16 chunk positions); every lane gets the total
__device__ __forceinline__ float red_j(float v) {
  v = dppadd<0x124>(v);  // row_ror:4  (bit 2)
  v = dppadd<0x128>(v);  // row_ror:8  (bit 3)
  v = pl16add(v);        // bit 4
  v = pl32add(v);        // bit 5
  return v;
}
// sum over lane bits 0,1 (row-quad)
__device__ __forceinline__ float red_q(float v) {
  v = dppadd<0xB1>(v);  // quad_perm xor1
  v = dppadd<0x4E>(v);  // quad_perm xor2
  return v;
}
// full 64-lane sum, all lanes get the result
__device__ __forceinline__ float red64(float v) { return red_j(red_q(v)); }

__global__ __launch_bounds__(NT, 2) void caps_kernel(
    const float* __restrict__ his, const float* __restrict__ itemeb,
    const int* __restrict__ mask, const float* __restrict__ W,
    const float* __restrict__ bias, float* __restrict__ out) {
  __shared__ float semb[NS * ND];  // 51200B: row s, chunk c at slot (c+rot(s))&15
  __shared__ float pe[8][NK][ND];  // 8192B: per-wave fused-BD partials
  __shared__ float sG[NK][ND];     // 1024B: running interest sum
  __shared__ float su[NK][ND];     // 1024B: u[k]; E1 se-bounce
  __shared__ float spv[NK][ND];    // 1024B: E h1 partials; interest stash
  __shared__ float smsk[NS];       // 800B
  __shared__ float4 pts4[8];       // 128B
  __shared__ __align__(16) float soff[NK];
  __shared__ float satt[NK];
  __shared__ int sidx;
  // ~63.4 KB -> 2 blocks/CU

  const int t = threadIdx.x;
  const int w = t >> 6, l = t & 63;
  const int g = l & 3, j = l >> 2;   // row-quad / chunk (DPP-aligned mapping)
  const int gid = (w << 2) | g;      // 0..31
  const int ke = w & 3, h_ = w >> 2; // E roles
  const int b = blockIdx.x;
  const float* eb = his + (size_t)b * NS * ND;

  // ---- W slice in regs: wave (ke,h) owns W[32h..32h+32)[64ke+l] ----
  float wreg[32];
#pragma unroll
  for (int c = 0; c < 32; ++c)
    wreg[c] = W[(size_t)(32 * h_ + c) * (NK * ND) + ke * ND + l];
  float breg = bias[ke * ND + l];
  float iq = itemeb[(size_t)b * ND + l];

  // ---- stage all 200 rows (linear LDS dest, rotated global source) ----
  {
    const int sg = l >> 4, sj = l & 15;  // staging-local lane roles
    for (int i = w; i < 50; i += 8) {
      int s = 4 * i + sg;
      int q = (sj - rot(s)) & 15;  // global chunk that lands at slot sj
      gload16(eb + (s << 6) + (q << 2), &semb[i * 256]);
    }
  }
  if (t < NS) smsk[t] = (mask[(size_t)b * NS + t] != 0) ? 1.0f : 0.0f;
  __syncthreads();

  const int ntr = (w < 2) ? 7 : 6;  // wave-uniform trips (gid<8 covers s=199)

  for (int it = 0; it < 3; ++it) {
    // ---- fused BD sweep: logits + softmax + e-accumulate, one emb read ----
    float4 a0 = {0, 0, 0, 0}, a1 = {0, 0, 0, 0}, a2 = {0, 0, 0, 0},
           a3 = {0, 0, 0, 0};
    float t0 = 0, t1 = 0, t2 = 0, t3 = 0;

    if (it == 0) {
      for (int tt = 0; tt < ntr; ++tt) {
        int s = gid + 32 * tt;
        float4 eq = *(const float4*)&semb[(s << 6) + 4 * ((j + rot(s)) & 15)];
        float sw = 0.25f * smsk[s];
        a0.x += sw * eq.x; a0.y += sw * eq.y;
        a0.z += sw * eq.z; a0.w += sw * eq.w;
        t0 += sw;
      }
      a0.x = red_q(a0.x); a0.y = red_q(a0.y);
      a0.z = red_q(a0.z); a0.w = red_q(a0.w);
      t0 = red_q(t0);
      a1 = a0; a2 = a0; a3 = a0; t1 = t0; t2 = t0; t3 = t0;
    } else {
      float4 u0 = *(const float4*)&su[0][4 * j];  // u chunks -> 16 VGPR
      float4 u1 = *(const float4*)&su[1][4 * j];
      float4 u2 = *(const float4*)&su[2][4 * j];
      float4 u3 = *(const float4*)&su[3][4 * j];
      float4 sof = *(const float4*)&soff[0];      // wave-broadcast
      for (int tt = 0; tt < ntr; ++tt) {
        int s = gid + 32 * tt;
        float4 eq = *(const float4*)&semb[(s << 6) + 4 * ((j + rot(s)) & 15)];
        float mk = smsk[s];
        // per-chunk logit partials; reduce over chunks on the VALU
        float lg0 = eq.x * u0.x + eq.y * u0.y + eq.z * u0.z + eq.w * u0.w;
        float lg1 = eq.x * u1.x + eq.y * u1.y + eq.z * u1.z + eq.w * u1.w;
        float lg2 = eq.x * u2.x + eq.y * u2.y + eq.z * u2.z + eq.w * u2.w;
        float lg3 = eq.x * u3.x + eq.y * u3.y + eq.z * u3.z + eq.w * u3.w;
        lg0 = red_j(lg0) + sof.x;
        lg1 = red_j(lg1) + sof.y;
        lg2 = red_j(lg2) + sof.z;
        lg3 = red_j(lg3) + sof.w;
        // in-lane softmax over k (redundant across the 16 chunk-lanes)
        float mx = fmaxf(fmaxf(lg0, lg1), fmaxf(lg2, lg3));
        float e0 = __expf(lg0 - mx), e1 = __expf(lg1 - mx);
        float e2 = __expf(lg2 - mx), e3 = __expf(lg3 - mx);
        float r = mk / (e0 + e1 + e2 + e3);
        float sw0 = e0 * r, sw1 = e1 * r, sw2 = e2 * r, sw3 = e3 * r;
        a0.x += sw0 * eq.x; a0.y += sw0 * eq.y; a0.z += sw0 * eq.z; a0.w += sw0 * eq.w;
        a1.x += sw1 * eq.x; a1.y += sw1 * eq.y; a1.z += sw1 * eq.z; a1.w += sw1 * eq.w;
        a2.x += sw2 * eq.x; a2.y += sw2 * eq.y; a2.z += sw2 * eq.z; a2.w += sw2 * eq.w;
        a3.x += sw3 * eq.x; a3.y += sw3 * eq.y; a3.z += sw3 * eq.z; a3.w += sw3 * eq.w;
        t0 += sw0; t1 += sw1; t2 += sw2; t3 += sw3;
      }
      // quad (cross-row-group) reduce on the VALU
      a0.x = red_q(a0.x); a0.y = red_q(a0.y); a0.z = red_q(a0.z); a0.w = red_q(a0.w);
      a1.x = red_q(a1.x); a1.y = red_q(a1.y); a1.z = red_q(a1.z); a1.w = red_q(a1.w);
      a2.x = red_q(a2.x); a2.y = red_q(a2.y); a2.z = red_q(a2.z); a2.w = red_q(a2.w);
      a3.x = red_q(a3.x); a3.y = red_q(a3.y); a3.z = red_q(a3.z); a3.w = red_q(a3.w);
      t0 = red_q(t0); t1 = red_q(t1); t2 = red_q(t2); t3 = red_q(t3);
    }
    if (g == 0) {  // 16 lanes, one float4 per chunk j
      *(float4*)&pe[w][0][4 * j] = a0;
      *(float4*)&pe[w][1][4 * j] = a1;
      *(float4*)&pe[w][2][4 * j] = a2;
      *(float4*)&pe[w][3][4 * j] = a3;
    }
    if (l == 0) pts4[w] = make_float4(t0, t1, t2, t3);
    __syncthreads();

    // ---- E1 (8 waves): wave (ke,h) reduces its 32-col half, dots wreg ----
    {
      int cl = 32 * h_ + (l & 31);
      float sse = 0.f;
#pragma unroll
      for (int w2 = 0; w2 < 8; ++w2) sse += pe[w2][ke][cl];
      su[ke][cl] = sse;  // same-wave write -> broadcast read (own half only)
      float vp = 0.f;
#pragma unroll
      for (int q2 = 0; q2 < 8; ++q2) {
        float4 e4 = *(const float4*)&su[ke][32 * h_ + 4 * q2];  // broadcast
        vp += e4.x * wreg[4 * q2 + 0] + e4.y * wreg[4 * q2 + 1] +
              e4.z * wreg[4 * q2 + 2] + e4.w * wreg[4 * q2 + 3];
      }
      if (h_) spv[ke][l] = vp;
      __syncthreads();

      // ---- E2 (waves 0-3): combine, squash, update G, fold A + soff ----
      if (h_ == 0) {
        float ts_ = 0.f;
#pragma unroll
        for (int w2 = 0; w2 < 8; ++w2) ts_ += ((const float*)&pts4[w2])[ke];
        float accv = vp + spv[ke][l] + ts_ * breg;
        float n2 = red64(accv * accv);
        float scale = n2 / (1.f + n2) / sqrtf(n2 + 1e-9f);
        float inter = scale * accv;
        if (it < 2) {
          float gnew = (it == 0) ? inter : (sG[ke][l] + inter);
          sG[ke][l] = gnew;
          float ob = red64(breg * gnew);
          if (l == 0) soff[ke] = ob;
          // A-fold: su[k][l] = W-row-l (cols 64k..) . G[k]
          const float4* Wr =
              (const float4*)(W + (size_t)l * (NK * ND) + ke * ND);
          const float4* Gk = (const float4*)&sG[ke][0];  // same-wave broadcast
          float a = 0.f;
#pragma unroll
          for (int d4 = 0; d4 < 16; ++d4) {
            float4 wv = Wr[d4], gv = Gk[d4];
            a += wv.x * gv.x + wv.y * gv.y + wv.z * gv.z + wv.w * gv.w;
          }
          su[ke][l] = a;
        } else {
          out[((size_t)b * NK + ke) * ND + l] = inter;
          float dot_ = red64(inter * iq);
          spv[ke][l] = inter;  // stash for argmax gather
          if (l == 0) satt[ke] = dot_;
        }
      }
      __syncthreads();
    }
  }

  // ---- readout: first-max argmax (== np.argmax) + gather ----
  if (t == 0) {
    int bi = 0;
    float bv = satt[0];
#pragma unroll
    for (int kk = 1; kk < NK; ++kk)
      if (satt[kk] > bv) { bv = satt[kk]; bi = kk; }
    sidx = bi;
  }
  __syncthreads();
  if (t < ND) out[(size_t)NB * NK * ND + (size_t)b * ND + t] = spv[sidx][t];
}

extern "C" void kernel_launch(void* const* d_in, const int* in_sizes, int n_in,
                              void* d_out, int out_size, void* d_ws, size_t ws_size,
                              hipStream_t stream) {
  (void)in_sizes; (void)n_in; (void)out_size; (void)d_ws; (void)ws_size;
  const float* his = (const float*)d_in[0];
  const float* itemeb = (const float*)d_in[1];
  const int* mask = (const int*)d_in[2];
  const float* W = (const float*)d_in[3];
  const float* bias = (const float*)d_in[4];
  float* out = (float*)d_out;
  caps_kernel<<<NB, NT, 0, stream>>>(his, itemeb, mask, W, bias, out);
}